// Round 8
// baseline (379.861 us; speedup 1.0000x reference)
//
#include <hip/hip_runtime.h>

#define SN 6400      // H*W
#define CN 256       // channels (= GEMM K)
#define NBATCH 2
#define NTILES 25    // SN / 256 (fixed-side row tiles)
#define NCHUNK 5     // streamed-side chunks (grid = 25*5*2 = 250 blocks, 1/CU)
#define TPC 5        // 256-wide streamed tiles per chunk
#define NSTG (TPC*4) // 20 stages per block (BK=64 per stage)

typedef _Float16 f16;
typedef f16 f16x8 __attribute__((ext_vector_type(8)));
typedef f16 f16x4 __attribute__((ext_vector_type(4)));
typedef float f32x4 __attribute__((ext_vector_type(4)));

__device__ __forceinline__ void gld16(const f16* g, f16* l) {
    __builtin_amdgcn_global_load_lds(
        (__attribute__((address_space(1))) void*)(g),
        (__attribute__((address_space(3))) void*)(l), 16, 0, 0);
}

// Stage a 256-row x 64-half (32 KB) region into LDS with 512 threads
// (4 gld16/thread). LDS row = 64 halfs = 128 B = 8 x 16B chunks; LDS chunk c
// holds global chunk c ^ (row&7) (swizzle on SOURCE address; DMA lane->LDS
// map fixed). Verified conflict-free (R0-R7: SQ_LDS_BANK_CONFLICT = 0).
__device__ __forceinline__ void stage64(const f16* __restrict__ g,
                                        f16* l, int tid) {
    #pragma unroll
    for (int it = 0; it < 4; ++it) {
        int q = it * 512 + tid;
        int row = q >> 3, c = q & 7;
        int cg = c ^ (row & 7);
        gld16(g + (size_t)row * CN + cg * 8, l + (q & ~63) * 8);
    }
}

// ---------------- prep kernels (unchanged) ----------------

__global__ __launch_bounds__(256) void k_meanT(const float* __restrict__ T,
                                               float* __restrict__ meanT) {
    int c = blockIdx.x, t = threadIdx.x;
    const float* p0 = T + (size_t)c * SN;
    const float* p1 = T + (size_t)(CN + c) * SN;
    float s = 0.f;
    for (int i = t; i < SN; i += 256) s += p0[i] + p1[i];
    #pragma unroll
    for (int d = 1; d < 64; d <<= 1) s += __shfl_xor(s, d, 64);
    __shared__ float sb[4];
    if ((t & 63) == 0) sb[t >> 6] = s;
    __syncthreads();
    if (t == 0) meanT[c] = (sb[0] + sb[1] + sb[2] + sb[3]) * (1.0f / 12800.0f);
}

// transpose [n,c,s] -> [n,s,c], center, cast to fp16 (normalized by k_nrm)
__global__ __launch_bounds__(256) void k_xpose(const float* __restrict__ X,
                                               const float* __restrict__ meanT,
                                               f16* __restrict__ out) {
    int n = blockIdx.z, c0 = blockIdx.y * 32, s0 = blockIdx.x * 64;
    __shared__ float tile[32][65];
    int tx = threadIdx.x & 63, ty = threadIdx.x >> 6;
    const float* Xb = X + ((size_t)n * CN + c0) * SN + s0;
    #pragma unroll
    for (int cy = ty; cy < 32; cy += 4)
        tile[cy][tx] = Xb[(size_t)cy * SN + tx] - meanT[c0 + cy];
    __syncthreads();
    int cc = threadIdx.x & 31, sy = threadIdx.x >> 5;
    f16* ob = out + ((size_t)n * SN + s0) * CN + c0;
    #pragma unroll
    for (int sr = sy; sr < 64; sr += 8)
        ob[(size_t)sr * CN + cc] = (f16)tile[cc][sr];
}

// fused: per-row sum-of-squares -> rsqrt -> in-place scale (one wave per row)
__global__ __launch_bounds__(256) void k_nrm(f16* __restrict__ Ah,
                                             f16* __restrict__ Bh) {
    int w = threadIdx.x >> 6, lane = threadIdx.x & 63;
    int idx = blockIdx.x * 4 + w;
    f16x4* pa = (f16x4*)(Ah + (size_t)idx * CN + lane * 4);
    f16x4* pb = (f16x4*)(Bh + (size_t)idx * CN + lane * 4);
    f16x4 a = *pa, b = *pb;
    float sa = 0.f, sb = 0.f;
    #pragma unroll
    for (int j = 0; j < 4; ++j) {
        float x = (float)a[j]; sa += x * x;
        float y = (float)b[j]; sb += y * y;
    }
    #pragma unroll
    for (int d = 1; d < 64; d <<= 1) {
        sa += __shfl_xor(sa, d, 64);
        sb += __shfl_xor(sb, d, 64);
    }
    float ra = rsqrtf(sa), rb = rsqrtf(sb);
    #pragma unroll
    for (int j = 0; j < 4; ++j) {
        a[j] = (f16)((float)a[j] * ra);
        b[j] = (f16)((float)b[j] * rb);
    }
    *pa = a; *pb = b;
}

// ---------------- fused GEMM passes ----------------
// R8: m201 geometry on R3's proven 2-barrier counted-vmcnt skeleton.
// 512 thr (8 waves, 2Mx4N), block tile 256x256, wave tile 128x64
// (acc 8x4 f32x4 = 128 VGPR), BK=64. Both A and B streamed per stage into a
// 64 KB combined buffer [A 32K | B 32K], double-buffered (128 KB LDS,
// 1 block/CU, buf index = ks&1 literal). Per stage: COMPUTE(buf) -> BAR ->
// issue DMA(s+2) into the just-read buf -> WAIT vmcnt(8) (drains DMA(s+1),
// leaves DMA(s+2) in flight ~2 stages) -> BAR. 64 MFMA + 24 ds_read_b128
// per wave per stage = 2x R3's work per barrier-pair (the R0-R7 evidence:
// dead time is ~constant per stage, so work/stage is the lever).
// PASS1's per-row g is staged once into a 1 KB LDS table (read in epilogue
// via ds_read -> lgkmcnt, OFF the vmcnt ledger; also saves 32 VGPR).
// PASS 0: per-row max of cos                          (fixed = I rows i)
// PASS 1: per-row sum of exp((10 - g_i*raw)/ln2)      (fixed = I rows i)
// PASS 2: per-row max over cols of (alpha_c - g_c*raw)(fixed = T rows j)
template <int PASS>
__global__ __launch_bounds__(512, 2) void k_gemm(const f16* __restrict__ A,
                                                 const f16* __restrict__ B,
                                                 const float* __restrict__ grow,
                                                 const float* __restrict__ alpha,
                                                 float* __restrict__ outP) {
    const int n = blockIdx.z, chunk = blockIdx.y, ft = blockIdx.x;
    const int tid = threadIdx.x, lane = tid & 63, wv = tid >> 6;
    const int wr = wv >> 2, wc = wv & 3, quad = lane >> 4, lrow = lane & 15;

    __shared__ f16 Sb[2][32768];    // 2 x 64 KB: [A 16384 halfs | B 16384]
    __shared__ float gldt[256];     // PASS1: per-row g table (1 KB)

    const f16* At = A + ((size_t)n * SN + (size_t)ft * 256) * CN;
    const f16* Bc = B + ((size_t)n * SN + (size_t)chunk * (TPC * 256)) * CN;

    // PASS1: stage the block's 256 per-row g values into LDS (one-time).
    if constexpr (PASS == 1) {
        if (tid < 256) gldt[tid] = grow[(size_t)n * SN + ft * 256 + tid];
        asm volatile("s_waitcnt lgkmcnt(0)" ::: "memory");
    }

    // ---- prologue: DMA stages 0 and 1 (A slice + B slice each) ----
    stage64(At,      Sb[0],         tid);   // s0 A (K 0..64)
    stage64(Bc,      Sb[0] + 16384, tid);   // s0 B (tile 0)
    stage64(At + 64, Sb[1],         tid);   // s1 A (K 64..128)
    stage64(Bc + 64, Sb[1] + 16384, tid);   // s1 B

    // per-lane LDS frag offsets (halfs). ra = wr*128 + mt*16 + lrow has
    // (ra&7)==(lrow&7) -> swizzle term mt-independent: frag mt at off + mt*1024.
    int offA[2], offB[2];
    #pragma unroll
    for (int kk = 0; kk < 2; ++kk) {
        int swz = ((kk * 4 + quad) ^ (lrow & 7)) * 8;
        offA[kk] = (wr * 128 + lrow) * 64 + swz;
        offB[kk] = 16384 + (wc * 64 + lrow) * 64 + swz;
    }

    float runRow[8][4];
    #pragma unroll
    for (int mt = 0; mt < 8; ++mt)
        #pragma unroll
        for (int v = 0; v < 4; ++v) runRow[mt][v] = (PASS == 1) ? 0.f : -3.0e38f;

    float gl[4], al[4];
    const float L2E = 1.44269504089f;
    const float TENL2E = 14.4269504089f;

    // outstanding: s0(8) + s1(8); vmcnt(8) drains s0
    asm volatile("s_waitcnt vmcnt(8)" ::: "memory");
    __builtin_amdgcn_s_barrier();

#define BAR()    __builtin_amdgcn_s_barrier()
#define WAIT8()  asm volatile("s_waitcnt vmcnt(8)" ::: "memory")
#define WAIT16() asm volatile("s_waitcnt vmcnt(16)" ::: "memory")
#define WAIT0()  asm volatile("s_waitcnt vmcnt(0)" ::: "memory")

// one BK=64 stage from Sb[BUF] (literal): 16+8 ds_read_b128, 64 MFMA
#define COMPUTE(BUF)                                                        \
    { _Pragma("unroll")                                                     \
      for (int kk = 0; kk < 2; ++kk) {                                      \
          f16x8 af[8]; f16x8 bf[4];                                         \
          _Pragma("unroll")                                                 \
          for (int mt = 0; mt < 8; ++mt)                                    \
              af[mt] = *(const f16x8*)&Sb[BUF][offA[kk] + mt * 1024];       \
          _Pragma("unroll")                                                 \
          for (int nt = 0; nt < 4; ++nt)                                    \
              bf[nt] = *(const f16x8*)&Sb[BUF][offB[kk] + nt * 1024];       \
          __builtin_amdgcn_s_setprio(1);                                    \
          _Pragma("unroll")                                                 \
          for (int mt = 0; mt < 8; ++mt)                                    \
              _Pragma("unroll")                                             \
              for (int nt = 0; nt < 4; ++nt)                                \
                  acc[mt][nt] = __builtin_amdgcn_mfma_f32_16x16x32_f16(     \
                      af[mt], bf[nt], acc[mt][nt], 0, 0, 0);                \
          __builtin_amdgcn_s_setprio(0);                                    \
      } }

#define ZEROACC()                                                           \
    { _Pragma("unroll")                                                     \
      for (int mt = 0; mt < 8; ++mt)                                        \
          _Pragma("unroll")                                                 \
          for (int nt = 0; nt < 4; ++nt)                                    \
              acc[mt][nt] = (f32x4){0.f, 0.f, 0.f, 0.f}; }

// per-tile epilogue (acc complete). PASS1 reads g from LDS (lgkm, not vmcnt).
#define EPILOGUE()                                                          \
    if constexpr (PASS == 0) {                                              \
        _Pragma("unroll")                                                   \
        for (int mt = 0; mt < 8; ++mt)                                      \
            _Pragma("unroll")                                               \
            for (int v = 0; v < 4; ++v) {                                   \
                float m = fmaxf(fmaxf(acc[mt][0][v], acc[mt][1][v]),        \
                                fmaxf(acc[mt][2][v], acc[mt][3][v]));       \
                runRow[mt][v] = fmaxf(runRow[mt][v], m);                    \
            }                                                               \
    } else if constexpr (PASS == 1) {                                       \
        _Pragma("unroll")                                                   \
        for (int mt = 0; mt < 8; ++mt) {                                    \
            f32x4 gv = *(const f32x4*)&gldt[wr * 128 + mt * 16 + quad * 4]; \
            _Pragma("unroll")                                               \
            for (int v = 0; v < 4; ++v) {                                   \
                float c1 = 0.5f * gv[v] * L2E;                              \
                float a0 = TENL2E - c1;                                     \
                float s2 = runRow[mt][v];                                   \
                _Pragma("unroll")                                           \
                for (int nt = 0; nt < 4; ++nt) {                            \
                    float arg = fminf(TENL2E,                               \
                                      fmaf(acc[mt][nt][v], c1, a0));        \
                    s2 += exp2f(arg);                                       \
                }                                                           \
                runRow[mt][v] = s2;                                         \
            }                                                               \
        }                                                                   \
    } else {                                                                \
        _Pragma("unroll")                                                   \
        for (int mt = 0; mt < 8; ++mt)                                      \
            _Pragma("unroll")                                               \
            for (int v = 0; v < 4; ++v) {                                   \
                _Pragma("unroll")                                           \
                for (int nt = 0; nt < 4; ++nt) {                            \
                    float raw = fmaxf(0.f,                                  \
                        fmaf(acc[mt][nt][v], -0.5f, 0.5f));                 \
                    float lc = fmaf(-gl[nt], raw, al[nt]);                  \
                    runRow[mt][v] = fmaxf(runRow[mt][v], lc);               \
                }                                                           \
            }                                                               \
    }

    f32x4 acc[8][4];

    // ---- main loop: t = 0..TPC-2, 4 literal-ks stages each ----
    #pragma unroll 1
    for (int t = 0; t < TPC - 1; ++t) {
        const f16* Bt = Bc + (size_t)t * (256 * CN);
        const f16* Bn = Bt + 256 * CN;

        ZEROACC();

        // ks0 (stage 4t, buf0)
        COMPUTE(0)
        BAR();
        stage64(At + 128, Sb[0], tid);            // DMA(4t+2) A (K 128..192)
        stage64(Bt + 128, Sb[0] + 16384, tid);    // DMA(4t+2) B
        if constexpr (PASS == 2) {
            #pragma unroll
            for (int nt = 0; nt < 4; ++nt) {
                int i = (chunk * TPC + t) * 256 + wc * 64 + nt * 16 + lrow;
                gl[nt] = grow[(size_t)n * SN + i];
                al[nt] = alpha[(size_t)n * SN + i];
            }
            WAIT16();   // drains DMA(4t+1) only (coeffs+DMA(4t+2) younger)
        } else {
            WAIT8();
        }
        BAR();

        // ks1 (stage 4t+1, buf1)
        COMPUTE(1)
        BAR();
        stage64(At + 192, Sb[1], tid);            // DMA(4t+3) A (K 192..256)
        stage64(Bt + 192, Sb[1] + 16384, tid);    // DMA(4t+3) B
        WAIT8();
        BAR();

        // ks2 (stage 4t+2, buf0)
        COMPUTE(0)
        BAR();
        stage64(At, Sb[0], tid);                  // DMA(4t+4): tile t+1, K 0..64
        stage64(Bn, Sb[0] + 16384, tid);
        WAIT8();
        BAR();

        // ks3 (stage 4t+3, buf1)
        COMPUTE(1)
        BAR();
        stage64(At + 64, Sb[1], tid);             // DMA(4t+5): tile t+1, K 64..128
        stage64(Bn + 64, Sb[1] + 16384, tid);
        EPILOGUE()                                 // overlaps in-flight DMA
        WAIT8();
        BAR();
    }

    // ---- peeled last tile (t = TPC-1): drain ----
    {
        const int t = TPC - 1;
        const f16* Bt = Bc + (size_t)t * (256 * CN);

        ZEROACC();

        COMPUTE(0)                                 // stage 16
        BAR();
        stage64(At + 128, Sb[0], tid);             // DMA(18)
        stage64(Bt + 128, Sb[0] + 16384, tid);
        if constexpr (PASS == 2) {
            #pragma unroll
            for (int nt = 0; nt < 4; ++nt) {
                int i = (chunk * TPC + t) * 256 + wc * 64 + nt * 16 + lrow;
                gl[nt] = grow[(size_t)n * SN + i];
                al[nt] = alpha[(size_t)n * SN + i];
            }
            WAIT16();
        } else {
            WAIT8();
        }
        BAR();

        COMPUTE(1)                                 // stage 17
        BAR();
        stage64(At + 192, Sb[1], tid);             // DMA(19)
        stage64(Bt + 192, Sb[1] + 16384, tid);
        WAIT8();
        BAR();

        COMPUTE(0)                                 // stage 18
        WAIT0();                                   // drain DMA(19)
        BAR();

        COMPUTE(1)                                 // stage 19
        EPILOGUE()
    }
#undef COMPUTE
#undef ZEROACC
#undef EPILOGUE
#undef BAR
#undef WAIT8
#undef WAIT16
#undef WAIT0

    // ---- cross-lane / cross-wave reduction (red aliased onto Sb) ----
    __syncthreads();                 // all waves done with Sb
    float* red = (float*)&Sb[0][0];
    #pragma unroll
    for (int mt = 0; mt < 8; ++mt)
        #pragma unroll
        for (int v = 0; v < 4; ++v) {
            float val = runRow[mt][v];
            #pragma unroll
            for (int d = 1; d < 16; d <<= 1) {
                float o = __shfl_xor(val, d, 64);
                val = (PASS == 1) ? (val + o) : fmaxf(val, o);
            }
            if (lrow == 0)
                red[wc * 256 + wr * 128 + mt * 16 + quad * 4 + v] = val;
        }
    __syncthreads();
    if (tid < 256) {
        float a = red[tid], b = red[256 + tid];
        float c = red[512 + tid], d = red[768 + tid];
        float r = (PASS == 1) ? (a + b + c + d)
                              : fmaxf(fmaxf(a, b), fmaxf(c, d));
        outP[(size_t)(n * NCHUNK + chunk) * SN + ft * 256 + tid] = r;
    }
}

// ---------------- small reduce kernels (unchanged) ----------------

__global__ __launch_bounds__(256) void r_g(const float* __restrict__ rowmaxP,
                                           float* __restrict__ grow) {
    int idx = blockIdx.x * 256 + threadIdx.x;
    int n = idx / SN, i = idx - n * SN;
    float m = -3.0e38f;
    for (int ch = 0; ch < NCHUNK; ++ch)
        m = fmaxf(m, rowmaxP[(size_t)(n * NCHUNK + ch) * SN + i]);
    float mr = fmaxf(0.f, (1.f - m) * 0.5f);
    grow[idx] = 10.f / (mr + 1e-5f);
}

__global__ __launch_bounds__(256) void r_alpha(const float* __restrict__ rowsumP,
                                               float* __restrict__ alpha) {
    int idx = blockIdx.x * 256 + threadIdx.x;
    int n = idx / SN, i = idx - n * SN;
    float s = 0.f;
    for (int ch = 0; ch < NCHUNK; ++ch)
        s += rowsumP[(size_t)(n * NCHUNK + ch) * SN + i];
    alpha[idx] = 10.f - logf(s);
}

__global__ __launch_bounds__(256) void r_colfin(const float* __restrict__ colmaxP,
                                                float* __restrict__ bsum) {
    int idx = blockIdx.x * 256 + threadIdx.x;
    int n = idx / SN, j = idx - n * SN;
    float m = -3.0e38f;
    for (int ch = 0; ch < NCHUNK; ++ch)
        m = fmaxf(m, colmaxP[(size_t)(n * NCHUNK + ch) * SN + j]);
    float v = expf(m);
    #pragma unroll
    for (int d = 1; d < 64; d <<= 1) v += __shfl_xor(v, d, 64);
    __shared__ float sb[4];
    if ((threadIdx.x & 63) == 0) sb[threadIdx.x >> 6] = v;
    __syncthreads();
    if (threadIdx.x == 0) bsum[blockIdx.x] = sb[0] + sb[1] + sb[2] + sb[3];
}

__global__ __launch_bounds__(64) void r_loss(const float* __restrict__ bsum,
                                             float* __restrict__ out) {
    int t = threadIdx.x;
    float v = (t < 50) ? bsum[t] : 0.f;
    float v0 = (t < 25) ? v : 0.f;
    float v1 = (t >= 25 && t < 50) ? v : 0.f;
    #pragma unroll
    for (int d = 1; d < 64; d <<= 1) {
        v0 += __shfl_xor(v0, d, 64);
        v1 += __shfl_xor(v1, d, 64);
    }
    if (t == 0) {
        float cs0 = v0 * (1.0f / SN), cs1 = v1 * (1.0f / SN);
        out[0] = -0.5f * (logf(cs0) + logf(cs1));
    }
}

// ---------------- launch ----------------

extern "C" void kernel_launch(void* const* d_in, const int* in_sizes, int n_in,
                              void* d_out, int out_size, void* d_ws, size_t ws_size,
                              hipStream_t stream) {
    const float* I = (const float*)d_in[0];
    const float* T = (const float*)d_in[1];
    float* out = (float*)d_out;

    float* wsf = (float*)d_ws;
    float* meanT = wsf;                        // 256
    float* grow  = meanT + 256;                // 12800
    float* alpha = grow + 12800;               // 12800
    float* rowmaxP = alpha + 12800;            // 64000
    float* rowsumP = rowmaxP + 64000;          // 64000
    float* colmaxP = rowsumP + 64000;          // 64000
    float* bsum = colmaxP + 64000;             // 64
    f16* Ah = (f16*)(bsum + 64);               // 2*6400*256 fp16 (centered I, [n,s,c])
    f16* Bh = Ah + (size_t)NBATCH * SN * CN;   // centered T; total ws ~14.1 MB

    k_meanT<<<256, 256, 0, stream>>>(T, meanT);
    k_xpose<<<dim3(100, 8, 2), 256, 0, stream>>>(I, meanT, Ah);
    k_xpose<<<dim3(100, 8, 2), 256, 0, stream>>>(T, meanT, Bh);
    k_nrm<<<3200, 256, 0, stream>>>(Ah, Bh);

    dim3 gg(NTILES, NCHUNK, NBATCH);
    k_gemm<0><<<gg, 512, 0, stream>>>(Ah, Bh, nullptr, nullptr, rowmaxP);
    r_g<<<50, 256, 0, stream>>>(rowmaxP, grow);
    k_gemm<1><<<gg, 512, 0, stream>>>(Ah, Bh, grow, nullptr, rowsumP);
    r_alpha<<<50, 256, 0, stream>>>(rowsumP, alpha);
    k_gemm<2><<<gg, 512, 0, stream>>>(Bh, Ah, grow, alpha, colmaxP);
    r_colfin<<<50, 256, 0, stream>>>(colmaxP, bsum);
    r_loss<<<1, 64, 0, stream>>>(bsum, out);
}